// Round 9
// baseline (238.268 us; speedup 1.0000x reference)
//
#include <hip/hip_runtime.h>

#define POOL 7
#define IMG_W 256
#define IMG_C 512
#define NUM_ROIS 1024

typedef float f4 __attribute__((ext_vector_type(4)));

// ---------------- single kernel: ROI pooling, direct indexing -------------
// R8 post-mortem: pinned-MLP probe was an in-regime NULL (>=14 loads
// guaranteed outstanding, time unchanged) -> pool is not latency-bound.
// R5 counters: FETCH+WRITE ~255 MB ~= compulsory -> not volume-bound.
// Remaining unprobed suspect: dispatch serialization. The 1-block sort
// kernel was a whole-GPU bubble (~3-5us on 1 CU) + a launch gap, serial
// in front of every pool run — and its only benefit (L2 read locality)
// is redundant because the whole 134 MB image L3-fits (R5: L3 absorbed
// ~250 MB of re-reads; FETCH stayed at compulsory).
// So: ONE dispatch. Block (roi, py) = (bid/7, bid%7), no sort, no
// workspace, no XCD swizzle (unsorted roi order is spatially random
// anyway). Pool body = R2 form, compiler-scheduled (lowest VGPR ->
// max occupancy; R8 proved the explicit MLP pin buys nothing).
__global__ __launch_bounds__(128) void roi_pool_kernel(
    const float* __restrict__ img,
    const int*   __restrict__ rois,
    float*       __restrict__ out)
{
    const int bid = blockIdx.x;            // 0..7167
    const int roi = bid / POOL;            // 0..1023
    const int py  = bid - roi * POOL;      // 0..6

    const int4 rb = ((const int4*)rois)[roi];
    const int x1  = __builtin_amdgcn_readfirstlane(rb.x);
    const int y1  = __builtin_amdgcn_readfirstlane(rb.y);
    const int x2  = __builtin_amdgcn_readfirstlane(rb.z);
    const int y2  = __builtin_amdgcn_readfirstlane(rb.w);

    const float h = (float)(y2 - y1);
    const float w = (float)(x2 - x1);
    const float sy = h / (float)POOL;      // reference numerics: h/P, then py*(h/P)
    const float sx = w / (float)POOL;

    const float ys = (float)py * sy;
    const int   y0 = (int)floorf(ys);
    const int   y1i = min(y0 + 1, max(y2 - y1 - 1, 0));
    const float wy = ys - (float)y0;

    const size_t rowstride = (size_t)IMG_W * IMG_C;
    const float* row0 = img + (size_t)(y1 + y0)  * rowstride;
    const float* row1 = img + (size_t)(y1 + y1i) * rowstride;

    const int t = threadIdx.x;             // 0..127
    const int cmax = max(x2 - x1 - 1, 0);

    f4* obase = (f4*)out + ((size_t)roi * (POOL * POOL) + (size_t)py * POOL) * (IMG_C / 4) + t;

#pragma unroll
    for (int px = 0; px < POOL; ++px) {
        const float xs = (float)px * sx;
        const int   x0 = (int)floorf(xs);
        const int   x1i = min(x0 + 1, cmax);
        const float wx = xs - (float)x0;
        const int c0 = x1 + x0, c1 = x1 + x1i;

        const f4 v00 = ((const f4*)(row0 + (size_t)c0 * IMG_C))[t];
        const f4 v01 = ((const f4*)(row0 + (size_t)c1 * IMG_C))[t];
        const f4 v10 = ((const f4*)(row1 + (size_t)c0 * IMG_C))[t];
        const f4 v11 = ((const f4*)(row1 + (size_t)c1 * IMG_C))[t];

        const float w00 = (1.0f - wy) * (1.0f - wx);
        const float w01 = (1.0f - wy) * wx;
        const float w10 = wy * (1.0f - wx);
        const float w11 = wy * wx;

        f4 o = v00 * w00 + v01 * w01 + v10 * w10 + v11 * w11;
        __builtin_nontemporal_store(o, obase + px * (IMG_C / 4));
    }
}

extern "C" void kernel_launch(void* const* d_in, const int* in_sizes, int n_in,
                              void* d_out, int out_size, void* d_ws, size_t ws_size,
                              hipStream_t stream) {
    const float* img  = (const float*)d_in[0];
    const int*   rois = (const int*)d_in[1];
    float* out = (float*)d_out;

    roi_pool_kernel<<<NUM_ROIS * POOL, 128, 0, stream>>>(img, rois, out);
}

// Round 11
// 237.872 us; speedup vs baseline: 1.0017x; 1.0017x over previous
//
#include <hip/hip_runtime.h>

#define POOL 7
#define IMG_W 256
#define IMG_C 512
#define NUM_ROIS 1024

typedef float f4 __attribute__((ext_vector_type(4)));

// ---------------- kernel 1: spatial counting-sort of ROI indices ----------
// Key = 32x32-px tile of (x1,y1), row-major: 8x8 = 64 buckets. One block,
// 1024 threads. Within-bucket order nondeterministic (LDS atomics) —
// harmless: main kernel writes out[roi] exactly once, any order.
// R9 A/B proved the sort is worth keeping: removing it cost +3.9 us and
// +35 MB FETCH (187 vs 152 MB) — XCD-chunked spatial locality is real.
__global__ __launch_bounds__(1024) void sort_rois_kernel(
    const int* __restrict__ rois, int4* __restrict__ sdesc)
{
    __shared__ int hist[64];
    __shared__ int base[64];
    const int tid = threadIdx.x;

    if (tid < 64) hist[tid] = 0;
    __syncthreads();

    const int4 rb = ((const int4*)rois)[tid];
    const int key = ((rb.y >> 5) << 3) | (rb.x >> 5);
    const int rank = atomicAdd(&hist[key], 1);
    __syncthreads();

    // wave-parallel exclusive prefix scan over the 64 buckets (one wave)
    if (tid < 64) {
        const int v = hist[tid];
        int inc = v;
#pragma unroll
        for (int d = 1; d < 64; d <<= 1) {
            const int n = __shfl_up(inc, d, 64);
            if (tid >= d) inc += n;
        }
        base[tid] = inc - v;
    }
    __syncthreads();

    const int dst = base[key] + rank;
    sdesc[dst] = (int4){rb.x, rb.y, rb.z, (rb.w << 10) | tid};
}

// ---------------- kernel 2: ROI pooling, per-(roi,py), L2-routed stores ---
// 7168 blocks x 128 threads, XCD i (bid&7) owns sorted chunk [i*128,(i+1)*128).
// Probe ledger: volume (R5: FETCH~compulsory), MLP (R8 asm-pin: in-regime
// null), occupancy (R5 vs R8: restored), VALU (R9: 5.8%), bank conflicts
// (0) — all nulled, yet HBM sits at 3.5 TB/s with no pipe saturated.
// Remaining mechanism: NT stores bypass L2, so the DRAM controllers see a
// fine interleave of scattered 2KB reads and 2KB writes (turnaround
// penalty). This version routes stores through L2 (plain store) so L2
// write-back aggregates the 100 MB output into large unidirectional
// drain bursts, decoupling read/write streams at the DRAM scheduler.
// Asm pin dropped (R8-vs-R2 null; VGPR 32 -> occupancy headroom).
__global__ __launch_bounds__(128) void roi_pool_kernel(
    const float* __restrict__ img,
    const int4*  __restrict__ sdesc,
    float*       __restrict__ out)
{
    const int bid  = blockIdx.x;           // 0..7167
    const int xcd  = bid & 7;
    const int slot = bid >> 3;             // 0..895
    const int sloc = slot / POOL;          // 0..127: position within chunk
    const int py   = slot - sloc * POOL;   // 0..6
    const int sidx = xcd * (NUM_ROIS / 8) + sloc;   // sorted position

    const int4 rb = sdesc[sidx];
    const int x1  = __builtin_amdgcn_readfirstlane(rb.x);
    const int y1  = __builtin_amdgcn_readfirstlane(rb.y);
    const int x2  = __builtin_amdgcn_readfirstlane(rb.z);
    const int w2  = __builtin_amdgcn_readfirstlane(rb.w);
    const int y2  = w2 >> 10;
    const int roi = w2 & 1023;

    const float h = (float)(y2 - y1);
    const float w = (float)(x2 - x1);
    const float sy = h / (float)POOL;      // reference numerics: h/P, then py*(h/P)
    const float sx = w / (float)POOL;

    const float ys = (float)py * sy;
    const int   y0 = (int)floorf(ys);
    const int   y1i = min(y0 + 1, max(y2 - y1 - 1, 0));
    const float wy = ys - (float)y0;

    const size_t rowstride = (size_t)IMG_W * IMG_C;
    const float* row0 = img + (size_t)(y1 + y0)  * rowstride;
    const float* row1 = img + (size_t)(y1 + y1i) * rowstride;

    const int t = threadIdx.x;             // 0..127
    const int cmax = max(x2 - x1 - 1, 0);

    f4* obase = (f4*)out + ((size_t)roi * (POOL * POOL) + (size_t)py * POOL) * (IMG_C / 4) + t;

#pragma unroll
    for (int px = 0; px < POOL; ++px) {
        const float xs = (float)px * sx;
        const int   x0 = (int)floorf(xs);
        const int   x1i = min(x0 + 1, cmax);
        const float wx = xs - (float)x0;
        const int c0 = x1 + x0, c1 = x1 + x1i;

        const f4 v00 = ((const f4*)(row0 + (size_t)c0 * IMG_C))[t];
        const f4 v01 = ((const f4*)(row0 + (size_t)c1 * IMG_C))[t];
        const f4 v10 = ((const f4*)(row1 + (size_t)c0 * IMG_C))[t];
        const f4 v11 = ((const f4*)(row1 + (size_t)c1 * IMG_C))[t];

        const float w00 = (1.0f - wy) * (1.0f - wx);
        const float w01 = (1.0f - wy) * wx;
        const float w10 = wy * (1.0f - wx);
        const float w11 = wy * wx;

        // plain store: route through L2 write-back (NOT nontemporal) so the
        // DRAM scheduler sees aggregated write bursts instead of a
        // read/write fine-grain interleave.
        obase[px * (IMG_C / 4)] = v00 * w00 + v01 * w01 + v10 * w10 + v11 * w11;
    }
}

extern "C" void kernel_launch(void* const* d_in, const int* in_sizes, int n_in,
                              void* d_out, int out_size, void* d_ws, size_t ws_size,
                              hipStream_t stream) {
    const float* img  = (const float*)d_in[0];
    const int*   rois = (const int*)d_in[1];
    float* out = (float*)d_out;
    int4* sdesc = (int4*)d_ws;             // 1024 int4, rewritten every call

    sort_rois_kernel<<<1, 1024, 0, stream>>>(rois, sdesc);
    roi_pool_kernel<<<NUM_ROIS * POOL, 128, 0, stream>>>(img, sdesc, out);
}

// Round 12
// 232.667 us; speedup vs baseline: 1.0241x; 1.0224x over previous
//
#include <hip/hip_runtime.h>

#define POOL 7
#define IMG_W 256
#define IMG_C 512
#define NUM_ROIS 1024

typedef float f4 __attribute__((ext_vector_type(4)));

// ---------------- kernel 1: spatial counting-sort of ROI indices ----------
// Key = 32x32-px tile of (x1,y1), row-major: 8x8 = 64 buckets. One block,
// 1024 threads. Within-bucket order nondeterministic (LDS atomics) —
// harmless: main kernel writes out[roi] exactly once, any order.
// R9 A/B: removing the sort cost +3.9 us and +35 MB FETCH — kept.
__global__ __launch_bounds__(1024) void sort_rois_kernel(
    const int* __restrict__ rois, int4* __restrict__ sdesc)
{
    __shared__ int hist[64];
    __shared__ int base[64];
    const int tid = threadIdx.x;

    if (tid < 64) hist[tid] = 0;
    __syncthreads();

    const int4 rb = ((const int4*)rois)[tid];
    const int key = ((rb.y >> 5) << 3) | (rb.x >> 5);
    const int rank = atomicAdd(&hist[key], 1);
    __syncthreads();

    // wave-parallel exclusive prefix scan over the 64 buckets (one wave)
    if (tid < 64) {
        const int v = hist[tid];
        int inc = v;
#pragma unroll
        for (int d = 1; d < 64; d <<= 1) {
            const int n = __shfl_up(inc, d, 64);
            if (tid >= d) inc += n;
        }
        base[tid] = inc - v;
    }
    __syncthreads();

    const int dst = base[key] + rank;
    sdesc[dst] = (int4){rb.x, rb.y, rb.z, (rb.w << 10) | tid};
}

// ---------------- kernel 2: ROI pooling (champion, R8 = 234.4 us) ---------
// 7168 blocks x 128 threads, XCD i (bid&7) owns sorted chunk
// [i*128,(i+1)*128). NT stores (R11 A/B: L2-routed stores +3.5 us worse —
// write-allocate evicts live image lines). Asm-pinned 28-load phase
// (R8's measured-best config; pin is null vs R2 but harmless).
__global__ __launch_bounds__(128, 2) void roi_pool_kernel(
    const float* __restrict__ img,
    const int4*  __restrict__ sdesc,
    float*       __restrict__ out)
{
    const int bid  = blockIdx.x;           // 0..7167
    const int xcd  = bid & 7;
    const int slot = bid >> 3;             // 0..895
    const int sloc = slot / POOL;          // 0..127: position within chunk
    const int py   = slot - sloc * POOL;   // 0..6
    const int sidx = xcd * (NUM_ROIS / 8) + sloc;   // sorted position

    const int4 rb = sdesc[sidx];
    const int x1  = __builtin_amdgcn_readfirstlane(rb.x);
    const int y1  = __builtin_amdgcn_readfirstlane(rb.y);
    const int x2  = __builtin_amdgcn_readfirstlane(rb.z);
    const int w2  = __builtin_amdgcn_readfirstlane(rb.w);
    const int y2  = w2 >> 10;
    const int roi = w2 & 1023;

    const float h = (float)(y2 - y1);
    const float w = (float)(x2 - x1);
    const float sy = h / (float)POOL;      // reference numerics: h/P, then py*(h/P)
    const float sx = w / (float)POOL;

    const float ys = (float)py * sy;
    const int   y0 = (int)floorf(ys);
    const int   y1i = min(y0 + 1, max(y2 - y1 - 1, 0));
    const float wy = ys - (float)y0;

    const size_t rowstride = (size_t)IMG_W * IMG_C;
    const float* row0 = img + (size_t)(y1 + y0)  * rowstride;
    const float* row1 = img + (size_t)(y1 + y1i) * rowstride;

    const int t = threadIdx.x;             // 0..127
    const int cmax = max(x2 - x1 - 1, 0);

    // ---- column indices + weights (uniform per block)
    int   c0a[POOL], c1a[POOL];
    float wxa[POOL];
#pragma unroll
    for (int px = 0; px < POOL; ++px) {
        const float xs = (float)px * sx;
        const int   x0 = (int)floorf(xs);
        c0a[px] = x1 + x0;
        c1a[px] = x1 + min(x0 + 1, cmax);
        wxa[px] = xs - (float)x0;
    }

    // ---- phase A: issue all 28 loads
    f4 v00[POOL], v01[POOL], v10[POOL], v11[POOL];
#pragma unroll
    for (int px = 0; px < POOL; ++px) {
        v00[px] = ((const f4*)(row0 + (size_t)c0a[px] * IMG_C))[t];
        v01[px] = ((const f4*)(row0 + (size_t)c1a[px] * IMG_C))[t];
        v10[px] = ((const f4*)(row1 + (size_t)c0a[px] * IMG_C))[t];
        v11[px] = ((const f4*)(row1 + (size_t)c1a[px] * IMG_C))[t];
    }

    // ---- pin: loads cannot sink below these asms; all 28 stay in flight
    asm volatile("" :
        "+v"(v00[0]), "+v"(v00[1]), "+v"(v00[2]), "+v"(v00[3]),
        "+v"(v00[4]), "+v"(v00[5]), "+v"(v00[6]),
        "+v"(v01[0]), "+v"(v01[1]), "+v"(v01[2]), "+v"(v01[3]),
        "+v"(v01[4]), "+v"(v01[5]), "+v"(v01[6]));
    asm volatile("" :
        "+v"(v10[0]), "+v"(v10[1]), "+v"(v10[2]), "+v"(v10[3]),
        "+v"(v10[4]), "+v"(v10[5]), "+v"(v10[6]),
        "+v"(v11[0]), "+v"(v11[1]), "+v"(v11[2]), "+v"(v11[3]),
        "+v"(v11[4]), "+v"(v11[5]), "+v"(v11[6]));

    // ---- phase B: weighted sums + NT stores
    f4* obase = (f4*)out + ((size_t)roi * (POOL * POOL) + (size_t)py * POOL) * (IMG_C / 4) + t;
#pragma unroll
    for (int px = 0; px < POOL; ++px) {
        const float wx = wxa[px];
        const float w00 = (1.0f - wy) * (1.0f - wx);
        const float w01 = (1.0f - wy) * wx;
        const float w10 = wy * (1.0f - wx);
        const float w11 = wy * wx;
        f4 o = v00[px] * w00 + v01[px] * w01 + v10[px] * w10 + v11[px] * w11;
        __builtin_nontemporal_store(o, obase + px * (IMG_C / 4));
    }
}

extern "C" void kernel_launch(void* const* d_in, const int* in_sizes, int n_in,
                              void* d_out, int out_size, void* d_ws, size_t ws_size,
                              hipStream_t stream) {
    const float* img  = (const float*)d_in[0];
    const int*   rois = (const int*)d_in[1];
    float* out = (float*)d_out;
    int4* sdesc = (int4*)d_ws;             // 1024 int4, rewritten every call

    sort_rois_kernel<<<1, 1024, 0, stream>>>(rois, sdesc);
    roi_pool_kernel<<<NUM_ROIS * POOL, 128, 0, stream>>>(img, sdesc, out);
}